// Round 1
// baseline (1358.969 us; speedup 1.0000x reference)
//
#include <hip/hip_runtime.h>
#include <cstdint>
#include <cstddef>

#define NH 4
#define NC 32
#define D 128
static constexpr float SCALE = 0.17677669529663687f;  // 1/sqrt(32)

// ---- order-preserving float<->uint keys for atomicMax on floats ----
__device__ __forceinline__ unsigned fkey(float f) {
  unsigned u = __float_as_uint(f);
  return (u & 0x80000000u) ? ~u : (u | 0x80000000u);
}
__device__ __forceinline__ float fdec(unsigned u) {
  return (u & 0x80000000u) ? __uint_as_float(u & 0x7fffffffu) : __uint_as_float(~u);
}

// x[i,:] = memory_table[n_id[i],:]
__global__ void k_gather(const float* __restrict__ mem, const int* __restrict__ n_id,
                         float* __restrict__ x, int N) {
  int row = blockIdx.x * 4 + (threadIdx.x >> 6);
  if (row >= N) return;
  int lane = threadIdx.x & 63;
  const float2* s = (const float2*)(mem + (size_t)n_id[row] * D);
  float2* d = (float2*)(x + (size_t)row * D);
  d[lane] = s[lane];
}

// q = x@Wq+bq ; k = x@Wk+bk ; v = x@Wv+bv ; agg = x@Ws+bs  (skip fused as agg-init)
__global__ void k_lin4(const float* __restrict__ x,
                       const float* __restrict__ Wq, const float* __restrict__ Wk,
                       const float* __restrict__ Wv, const float* __restrict__ Ws,
                       const float* __restrict__ bq, const float* __restrict__ bk,
                       const float* __restrict__ bv, const float* __restrict__ bs,
                       float* __restrict__ q, float* __restrict__ k,
                       float* __restrict__ v, float* __restrict__ agg, int N) {
  __shared__ float xs[16][128];
  int r0 = blockIdx.x * 16;
  for (int t = threadIdx.x; t < 16 * 32; t += 256) {
    int r = t >> 5, c4 = t & 31;
    if (r0 + r < N)
      ((float4*)xs[r])[c4] = ((const float4*)(x + (size_t)(r0 + r) * D))[c4];
  }
  __syncthreads();
  int c = threadIdx.x & 127;
  int rh = (threadIdx.x >> 7) * 8;  // row-half: 0 or 8
  const float* Wm[4] = {Wq, Wk, Wv, Ws};
  const float* bm[4] = {bq, bk, bv, bs};
  float* om[4] = {q, k, v, agg};
#pragma unroll
  for (int mi = 0; mi < 4; mi++) {
    const float* __restrict__ W = Wm[mi];
    float b = bm[mi][c];
    float acc[8];
#pragma unroll
    for (int r = 0; r < 8; r++) acc[r] = b;
    for (int kk = 0; kk < D; kk += 4) {
      float w0 = W[(kk + 0) * D + c];
      float w1 = W[(kk + 1) * D + c];
      float w2 = W[(kk + 2) * D + c];
      float w3 = W[(kk + 3) * D + c];
#pragma unroll
      for (int r = 0; r < 8; r++) {
        float4 xv = *(const float4*)&xs[rh + r][kk];
        acc[r] += xv.x * w0 + xv.y * w1 + xv.z * w2 + xv.w * w3;
      }
    }
    float* __restrict__ o = om[mi];
#pragma unroll
    for (int r = 0; r < 8; r++)
      if (r0 + rh + r < N) o[(size_t)(r0 + rh + r) * D + c] = acc[r];
  }
}

// e[edge,:] = pe[edge,:] @ We   where pe = concat(ea[:, :3], ea[:, 4:66], et_emb[etype])
__global__ void k_egemm(const float* __restrict__ ea, const float* __restrict__ et_emb,
                        const float* __restrict__ We, float* __restrict__ e, int E) {
  __shared__ float ps[16][76];
  int e0 = blockIdx.x * 16;
  for (int t = threadIdx.x; t < 16 * 73; t += 256) {
    int r = t / 73, j = t - r * 73;
    int edge = e0 + r;
    float val = 0.f;
    if (edge < E) {
      const float* row = ea + (size_t)edge * 66;
      if (j < 3) val = row[j];
      else if (j < 65) val = row[j + 1];
      else {
        int et = (int)row[3];
        val = et_emb[et * 8 + (j - 65)];
      }
    }
    ps[r][j] = val;
  }
  __syncthreads();
  int c = threadIdx.x & 127;
  int rh = (threadIdx.x >> 7) * 8;
  float acc[8] = {0.f, 0.f, 0.f, 0.f, 0.f, 0.f, 0.f, 0.f};
  for (int kk = 0; kk < 73; kk++) {
    float w = We[kk * D + c];
#pragma unroll
    for (int r = 0; r < 8; r++) acc[r] += ps[rh + r][kk] * w;
  }
#pragma unroll
  for (int r = 0; r < 8; r++)
    if (e0 + rh + r < E) e[(size_t)(e0 + rh + r) * D + c] = acc[r];
}

// score[edge,h] = SCALE * dot(q[dst], k[src]+e[edge]) per head; atomicMax into m[dst,h]
__global__ void k_score(const float* __restrict__ q, const float* __restrict__ kmat,
                        const float* __restrict__ e, const int* __restrict__ src,
                        const int* __restrict__ dst, float* __restrict__ sc,
                        unsigned* __restrict__ m, int E) {
  int edge = blockIdx.x * 4 + (threadIdx.x >> 6);
  if (edge >= E) return;
  int lane = threadIdx.x & 63;
  int s = src[edge], d = dst[edge];
  const float* qp = q + (size_t)d * D;
  const float* kp = kmat + (size_t)s * D;
  const float* ep = e + (size_t)edge * D;
  float p0 = qp[lane] * (kp[lane] + ep[lane]);
  float p1 = qp[lane + 64] * (kp[lane + 64] + ep[lane + 64]);
#pragma unroll
  for (int off = 16; off >= 1; off >>= 1) {
    p0 += __shfl_xor(p0, off);
    p1 += __shfl_xor(p1, off);
  }
  if ((lane & 31) == 0) {
    int h = lane >> 5;  // 0 or 1
    float s0 = p0 * SCALE;  // head h
    float s1 = p1 * SCALE;  // head h+2
    sc[(size_t)edge * 4 + h] = s0;
    sc[(size_t)edge * 4 + 2 + h] = s1;
    atomicMax(&m[d * 4 + h], fkey(s0));
    atomicMax(&m[d * 4 + 2 + h], fkey(s1));
  }
}

// sc <- exp(sc - m[dst]) in place; den[dst,h] += ex
__global__ void k_ex(float* __restrict__ sc, const unsigned* __restrict__ m,
                     const int* __restrict__ dst, float* __restrict__ den, int E) {
  int t = blockIdx.x * 256 + threadIdx.x;
  if (t >= E * 4) return;
  int edge = t >> 2, h = t & 3;
  int d = dst[edge];
  float ex = __expf(sc[t] - fdec(m[d * 4 + h]));
  sc[t] = ex;
  atomicAdd(&den[d * 4 + h], ex);
}

// agg[dst,:] += (v[src]+e[edge]) * alpha  (alpha = ex/(den+1e-16))
__global__ void k_agg(const float* __restrict__ vmat, const float* __restrict__ e,
                      const float* __restrict__ sc, const float* __restrict__ den,
                      const int* __restrict__ src, const int* __restrict__ dst,
                      float* __restrict__ agg, int E) {
  int edge = blockIdx.x * 4 + (threadIdx.x >> 6);
  if (edge >= E) return;
  int lane = threadIdx.x & 63;
  int s = src[edge], d = dst[edge];
  int h = lane >> 5;  // 0/1 -> heads h and h+2
  float a0 = sc[(size_t)edge * 4 + h] / (den[d * 4 + h] + 1e-16f);
  float a1 = sc[(size_t)edge * 4 + 2 + h] / (den[d * 4 + 2 + h] + 1e-16f);
  float v0 = (vmat[(size_t)s * D + lane] + e[(size_t)edge * D + lane]) * a0;
  float v1 = (vmat[(size_t)s * D + lane + 64] + e[(size_t)edge * D + lane + 64]) * a1;
  atomicAdd(&agg[(size_t)d * D + lane], v0);
  atomicAdd(&agg[(size_t)d * D + lane + 64], v1);
}

__global__ void k_relu(float* __restrict__ x, int n4) {
  int t = blockIdx.x * 256 + threadIdx.x;
  if (t >= n4) return;
  float4 v = ((float4*)x)[t];
  v.x = fmaxf(v.x, 0.f); v.y = fmaxf(v.y, 0.f);
  v.z = fmaxf(v.z, 0.f); v.w = fmaxf(v.w, 0.f);
  ((float4*)x)[t] = v;
}

extern "C" void kernel_launch(void* const* d_in, const int* in_sizes, int n_in,
                              void* d_out, int out_size, void* d_ws, size_t ws_size,
                              hipStream_t stream) {
  const float* mem  = (const float*)d_in[0];
  const float* ea   = (const float*)d_in[1];
  const float* etem = (const float*)d_in[2];
  const float* W[18];
  for (int i = 0; i < 18; i++) W[i] = (const float*)d_in[3 + i];
  const int* n_id = (const int*)d_in[21];
  const int* eidx = (const int*)d_in[22];
  const int N = in_sizes[21];
  const int E = in_sizes[22] / 2;
  const int* srcp = eidx;
  const int* dstp = eidx + E;

  // workspace layout (fp32)
  float* x0 = (float*)d_ws;                 // N*128
  float* x1 = x0 + (size_t)N * D;           // N*128
  float* q  = x1 + (size_t)N * D;           // N*128
  float* k  = q  + (size_t)N * D;           // N*128
  float* v  = k  + (size_t)N * D;           // N*128
  float* e  = v  + (size_t)N * D;           // E*128
  float* sc = e  + (size_t)E * D;           // E*4 (score, then ex in place)
  unsigned* m = (unsigned*)(sc + (size_t)E * 4);  // N*4
  float* den = (float*)(m + (size_t)N * 4);       // N*4

  float* out = (float*)d_out;
  dim3 b256(256);

  k_gather<<<dim3((N + 3) / 4), b256, 0, stream>>>(mem, n_id, x0, N);

  for (int layer = 0; layer < 2; layer++) {
    const float* Wq = W[layer * 9 + 0];
    const float* Wk = W[layer * 9 + 1];
    const float* Wv = W[layer * 9 + 2];
    const float* We = W[layer * 9 + 3];
    const float* Ws = W[layer * 9 + 4];
    const float* bq = W[layer * 9 + 5];
    const float* bk = W[layer * 9 + 6];
    const float* bv = W[layer * 9 + 7];
    const float* bs = W[layer * 9 + 8];
    const float* xc = (layer == 0) ? x0 : x1;
    float* agg = (layer == 0) ? x1 : out;

    hipMemsetAsync(m, 0, (size_t)N * 8 * sizeof(unsigned), stream);  // zeros m AND den
    k_lin4<<<dim3((N + 15) / 16), b256, 0, stream>>>(xc, Wq, Wk, Wv, Ws,
                                                     bq, bk, bv, bs, q, k, v, agg, N);
    k_egemm<<<dim3((E + 15) / 16), b256, 0, stream>>>(ea, etem, We, e, E);
    k_score<<<dim3((E + 3) / 4), b256, 0, stream>>>(q, k, e, srcp, dstp, sc, m, E);
    k_ex<<<dim3((E * 4 + 255) / 256), b256, 0, stream>>>(sc, m, dstp, den, E);
    k_agg<<<dim3((E + 3) / 4), b256, 0, stream>>>(v, e, sc, den, srcp, dstp, agg, E);
    if (layer == 0)
      k_relu<<<dim3((N * D / 4 + 255) / 256), b256, 0, stream>>>(x1, N * D / 4);
  }
}

// Round 2
// 1160.700 us; speedup vs baseline: 1.1708x; 1.1708x over previous
//
#include <hip/hip_runtime.h>
#include <cstdint>
#include <cstddef>

#define D 128
static constexpr float SCALE = 0.17677669529663687f;  // 1/sqrt(32)

typedef __attribute__((ext_vector_type(8))) short bf16x8;
typedef __attribute__((ext_vector_type(4))) float f32x4;

__device__ __forceinline__ unsigned short f2b(float f) {
  unsigned u = __float_as_uint(f);
  return (unsigned short)((u + 0x7fffu + ((u >> 16) & 1u)) >> 16);  // RNE
}
__device__ __forceinline__ float2 b2f2(unsigned u) {
  float2 r;
  r.x = __uint_as_float(u << 16);
  r.y = __uint_as_float(u & 0xffff0000u);
  return r;
}
__device__ __forceinline__ unsigned fkey(float f) {
  unsigned u = __float_as_uint(f);
  return (u & 0x80000000u) ? ~u : (u | 0x80000000u);
}
__device__ __forceinline__ float fdec(unsigned u) {
  return (u & 0x80000000u) ? __uint_as_float(u & 0x7fffffffu) : __uint_as_float(~u);
}

// x[i,:] = memory_table[n_id[i],:]
__global__ void k_gather(const float* __restrict__ mem, const int* __restrict__ n_id,
                         float* __restrict__ x, int N) {
  int row = blockIdx.x * 4 + (threadIdx.x >> 6);
  if (row >= N) return;
  int lane = threadIdx.x & 63;
  const float2* s = (const float2*)(mem + (size_t)n_id[row] * D);
  float2* d = (float2*)(x + (size_t)row * D);
  d[lane] = s[lane];
}

// Convert weights to bf16, transposed [n][k]. Per layer: WqT,WkT,WvT,WsT (128x128)
// then WeT (128x96, k>=73 zero). Layer stride 77824 elems.
__global__ void k_prep_w(const float* Wq1, const float* Wk1, const float* Wv1,
                         const float* Ws1, const float* We1,
                         const float* Wq2, const float* Wk2, const float* Wv2,
                         const float* Ws2, const float* We2,
                         unsigned short* __restrict__ wt) {
  int i = blockIdx.x * 256 + threadIdx.x;
  if (i >= 2 * 77824) return;
  int l = i / 77824, j = i - l * 77824;
  const float* Wm[10] = {Wq1, Wk1, Wv1, Ws1, We1, Wq2, Wk2, Wv2, Ws2, We2};
  float val;
  if (j < 65536) {
    int m = j >> 14, idx = j & 16383, n = idx >> 7, k = idx & 127;
    val = Wm[l * 5 + m][k * 128 + n];
  } else {
    int jj = j - 65536, n = jj / 96, k = jj - (jj / 96) * 96;
    val = (k < 73) ? Wm[l * 5 + 4][k * 128 + n] : 0.f;
  }
  wt[i] = f2b(val);
}

// q,k,v (bf16) and agg=x@Ws+bs (f32, skip fused) via MFMA. 64 rows/block.
__global__ __launch_bounds__(256) void k_lin4_mfma(
    const float* __restrict__ x, const unsigned short* __restrict__ wt,
    const float* __restrict__ bq, const float* __restrict__ bk,
    const float* __restrict__ bv, const float* __restrict__ bs,
    unsigned short* __restrict__ q, unsigned short* __restrict__ k,
    unsigned short* __restrict__ v, float* __restrict__ agg, int N) {
  __shared__ unsigned short xS[64 * 136];
  __shared__ unsigned short wS[128 * 136];
  int r0 = blockIdx.x * 64;
  int tid = threadIdx.x;
  for (int ch = tid; ch < 2048; ch += 256) {  // stage x fp32->bf16
    int r = ch >> 5, c4 = ch & 31;
    float4 xv = ((const float4*)(x + (size_t)(r0 + r) * D))[c4];
    unsigned short* dst = &xS[r * 136 + c4 * 4];
    dst[0] = f2b(xv.x); dst[1] = f2b(xv.y); dst[2] = f2b(xv.z); dst[3] = f2b(xv.w);
  }
  int wave = tid >> 6, lane = tid & 63;
  int mrow = lane & 15, kgrp = lane >> 4;
  const float* bias[4] = {bq, bk, bv, bs};
  for (int mi = 0; mi < 4; mi++) {
    __syncthreads();
    const uint4* wg = (const uint4*)(wt + mi * 16384);
    for (int ch = tid; ch < 2048; ch += 256) {
      int n = ch >> 4, k8 = (ch & 15) << 3;
      *(uint4*)&wS[n * 136 + k8] = wg[ch];
    }
    __syncthreads();
    f32x4 acc[8];
#pragma unroll
    for (int nt = 0; nt < 8; nt++) {
      float b = bias[mi][mrow + 16 * nt];
      acc[nt] = (f32x4){b, b, b, b};
    }
#pragma unroll
    for (int kt = 0; kt < 4; kt++) {
      bf16x8 a = *(const bf16x8*)&xS[(wave * 16 + mrow) * 136 + kt * 32 + kgrp * 8];
#pragma unroll
      for (int nt = 0; nt < 8; nt++) {
        bf16x8 b = *(const bf16x8*)&wS[(mrow + 16 * nt) * 136 + kt * 32 + kgrp * 8];
        acc[nt] = __builtin_amdgcn_mfma_f32_16x16x32_bf16(a, b, acc[nt], 0, 0, 0);
      }
    }
    int row0 = r0 + wave * 16 + kgrp * 4;
    if (mi < 3) {
      unsigned short* o = (mi == 0) ? q : ((mi == 1) ? k : v);
#pragma unroll
      for (int nt = 0; nt < 8; nt++) {
        int col = mrow + 16 * nt;
#pragma unroll
        for (int r = 0; r < 4; r++)
          if (row0 + r < N) o[(size_t)(row0 + r) * D + col] = f2b(acc[nt][r]);
      }
    } else {
#pragma unroll
      for (int nt = 0; nt < 8; nt++) {
        int col = mrow + 16 * nt;
#pragma unroll
        for (int r = 0; r < 4; r++)
          if (row0 + r < N) agg[(size_t)(row0 + r) * D + col] = acc[nt][r];
      }
    }
  }
}

// e = pe @ We (bf16 out). pe built in LDS from ea + et_emb. 64 edges/block.
__global__ __launch_bounds__(256) void k_egemm_mfma(
    const float* __restrict__ ea, const float* __restrict__ et_emb,
    const unsigned short* __restrict__ weT, unsigned short* __restrict__ e, int E) {
  __shared__ unsigned short pS[64 * 104];
  __shared__ unsigned short wS[128 * 104];
  int e0 = blockIdx.x * 64;
  int tid = threadIdx.x;
  const uint4* wg = (const uint4*)weT;
  for (int ch = tid; ch < 1536; ch += 256) {
    int n = ch / 12, k8 = (ch % 12) << 3;
    *(uint4*)&wS[n * 104 + k8] = wg[ch];
  }
  for (int t = tid; t < 64 * 66; t += 256) {
    int r = t / 66, j = t - (t / 66) * 66;
    float val = ea[(size_t)(e0 + r) * 66 + j];
    if (j < 3) pS[r * 104 + j] = f2b(val);
    else if (j == 3) {
      int et = (int)val;
#pragma unroll
      for (int u = 0; u < 8; u++) pS[r * 104 + 65 + u] = f2b(et_emb[et * 8 + u]);
    } else pS[r * 104 + j - 1] = f2b(val);
  }
  for (int t = tid; t < 64 * 23; t += 256) {  // zero pad k=73..95
    int r = t / 23, j = 73 + t - (t / 23) * 23;
    pS[r * 104 + j] = 0;
  }
  __syncthreads();
  int wave = tid >> 6, lane = tid & 63;
  int mrow = lane & 15, kgrp = lane >> 4;
  f32x4 acc[8] = {};
#pragma unroll
  for (int kt = 0; kt < 3; kt++) {
    bf16x8 a = *(const bf16x8*)&pS[(wave * 16 + mrow) * 104 + kt * 32 + kgrp * 8];
#pragma unroll
    for (int nt = 0; nt < 8; nt++) {
      bf16x8 b = *(const bf16x8*)&wS[(mrow + 16 * nt) * 104 + kt * 32 + kgrp * 8];
      acc[nt] = __builtin_amdgcn_mfma_f32_16x16x32_bf16(a, b, acc[nt], 0, 0, 0);
    }
  }
  int row0 = e0 + wave * 16 + kgrp * 4;
#pragma unroll
  for (int nt = 0; nt < 8; nt++) {
    int col = mrow + 16 * nt;
#pragma unroll
    for (int r = 0; r < 4; r++)
      if (row0 + r < E) e[(size_t)(row0 + r) * D + col] = f2b(acc[nt][r]);
  }
}

// score per edge/head; atomicMax into m. bf16 inputs, lane covers 2 cols.
__global__ void k_score(const unsigned short* __restrict__ q,
                        const unsigned short* __restrict__ kmat,
                        const unsigned short* __restrict__ e,
                        const int* __restrict__ src, const int* __restrict__ dst,
                        float* __restrict__ sc, unsigned* __restrict__ m, int E) {
  int edge = blockIdx.x * 4 + (threadIdx.x >> 6);
  if (edge >= E) return;
  int lane = threadIdx.x & 63;
  int s = src[edge], d = dst[edge];
  unsigned qv = ((const unsigned*)q)[(size_t)d * 64 + lane];
  unsigned kv = ((const unsigned*)kmat)[(size_t)s * 64 + lane];
  unsigned ev = ((const unsigned*)e)[(size_t)edge * 64 + lane];
  float2 qf = b2f2(qv), kf = b2f2(kv), ef = b2f2(ev);
  float p = qf.x * (kf.x + ef.x) + qf.y * (kf.y + ef.y);
  p += __shfl_xor(p, 8); p += __shfl_xor(p, 4);
  p += __shfl_xor(p, 2); p += __shfl_xor(p, 1);
  if ((lane & 15) == 0) {
    int h = lane >> 4;
    float sv = p * SCALE;
    sc[(size_t)edge * 4 + h] = sv;
    atomicMax(&m[d * 4 + h], fkey(sv));
  }
}

// sc <- exp(sc - m[dst]); den += ex
__global__ void k_ex(float* __restrict__ sc, const unsigned* __restrict__ m,
                     const int* __restrict__ dst, float* __restrict__ den, int E) {
  int t = blockIdx.x * 256 + threadIdx.x;
  if (t >= E * 4) return;
  int edge = t >> 2, h = t & 3;
  int d = dst[edge];
  float ex = __expf(sc[t] - fdec(m[d * 4 + h]));
  sc[t] = ex;
  atomicAdd(&den[d * 4 + h], ex);
}

// agg[dst] += (v[src]+e)*alpha
__global__ void k_agg(const unsigned short* __restrict__ vmat,
                      const unsigned short* __restrict__ e,
                      const float* __restrict__ sc, const float* __restrict__ den,
                      const int* __restrict__ src, const int* __restrict__ dst,
                      float* __restrict__ agg, int E) {
  int edge = blockIdx.x * 4 + (threadIdx.x >> 6);
  if (edge >= E) return;
  int lane = threadIdx.x & 63;
  int s = src[edge], d = dst[edge];
  int h = lane >> 4;
  float a = sc[(size_t)edge * 4 + h] / (den[d * 4 + h] + 1e-16f);
  unsigned vv = ((const unsigned*)vmat)[(size_t)s * 64 + lane];
  unsigned ev = ((const unsigned*)e)[(size_t)edge * 64 + lane];
  float2 vf = b2f2(vv), ef = b2f2(ev);
  atomicAdd(&agg[(size_t)d * D + 2 * lane], (vf.x + ef.x) * a);
  atomicAdd(&agg[(size_t)d * D + 2 * lane + 1], (vf.y + ef.y) * a);
}

__global__ void k_relu(float* __restrict__ x, int n4) {
  int t = blockIdx.x * 256 + threadIdx.x;
  if (t >= n4) return;
  float4 v = ((float4*)x)[t];
  v.x = fmaxf(v.x, 0.f); v.y = fmaxf(v.y, 0.f);
  v.z = fmaxf(v.z, 0.f); v.w = fmaxf(v.w, 0.f);
  ((float4*)x)[t] = v;
}

extern "C" void kernel_launch(void* const* d_in, const int* in_sizes, int n_in,
                              void* d_out, int out_size, void* d_ws, size_t ws_size,
                              hipStream_t stream) {
  const float* mem  = (const float*)d_in[0];
  const float* ea   = (const float*)d_in[1];
  const float* etem = (const float*)d_in[2];
  const float* W[18];
  for (int i = 0; i < 18; i++) W[i] = (const float*)d_in[3 + i];
  const int* n_id = (const int*)d_in[21];
  const int* eidx = (const int*)d_in[22];
  const int N = in_sizes[21];
  const int E = in_sizes[22] / 2;
  const int* srcp = eidx;
  const int* dstp = eidx + E;

  // workspace layout
  float* x0 = (float*)d_ws;                         // N*128 f32
  float* x1 = x0 + (size_t)N * D;                   // N*128 f32
  unsigned short* q = (unsigned short*)(x1 + (size_t)N * D);  // N*128 bf16
  unsigned short* k = q + (size_t)N * D;
  unsigned short* v = k + (size_t)N * D;
  unsigned short* e = v + (size_t)N * D;            // E*128 bf16
  float* sc = (float*)(e + (size_t)E * D);          // E*4 f32
  unsigned* m = (unsigned*)(sc + (size_t)E * 4);    // N*4
  float* den = (float*)(m + (size_t)N * 4);         // N*4
  unsigned short* wt = (unsigned short*)(den + (size_t)N * 4);  // 2*77824 bf16

  float* out = (float*)d_out;
  dim3 b256(256);

  k_prep_w<<<dim3((2 * 77824 + 255) / 256), b256, 0, stream>>>(
      W[0], W[1], W[2], W[4], W[3], W[9], W[10], W[11], W[13], W[12], wt);
  k_gather<<<dim3((N + 3) / 4), b256, 0, stream>>>(mem, n_id, x0, N);

  for (int layer = 0; layer < 2; layer++) {
    const float* bq = W[layer * 9 + 5];
    const float* bk = W[layer * 9 + 6];
    const float* bv = W[layer * 9 + 7];
    const float* bs = W[layer * 9 + 8];
    const float* xc = (layer == 0) ? x0 : x1;
    float* agg = (layer == 0) ? x1 : out;
    const unsigned short* wtl = wt + (size_t)layer * 77824;

    hipMemsetAsync(m, 0, (size_t)N * 8 * sizeof(unsigned), stream);  // m AND den
    k_lin4_mfma<<<dim3((N + 63) / 64), b256, 0, stream>>>(
        xc, wtl, bq, bk, bv, bs, q, k, v, agg, N);
    k_egemm_mfma<<<dim3((E + 63) / 64), b256, 0, stream>>>(
        ea, etem, wtl + 65536, e, E);
    k_score<<<dim3((E + 3) / 4), b256, 0, stream>>>(q, k, e, srcp, dstp, sc, m, E);
    k_ex<<<dim3((E * 4 + 255) / 256), b256, 0, stream>>>(sc, m, dstp, den, E);
    k_agg<<<dim3((E + 3) / 4), b256, 0, stream>>>(v, e, sc, den, srcp, dstp, agg, E);
    if (layer == 0)
      k_relu<<<dim3((N * D / 4 + 255) / 256), b256, 0, stream>>>(x1, N * D / 4);
  }
}

// Round 3
// 689.846 us; speedup vs baseline: 1.9700x; 1.6826x over previous
//
#include <hip/hip_runtime.h>
#include <cstdint>
#include <cstddef>

#define D 128
static constexpr float SCALE = 0.17677669529663687f;  // 1/sqrt(32)

typedef __attribute__((ext_vector_type(8))) short bf16x8;
typedef __attribute__((ext_vector_type(4))) float f32x4;

__device__ __forceinline__ unsigned short f2b(float f) {
  unsigned u = __float_as_uint(f);
  return (unsigned short)((u + 0x7fffu + ((u >> 16) & 1u)) >> 16);  // RNE
}
__device__ __forceinline__ float2 b2f2(unsigned u) {
  float2 r;
  r.x = __uint_as_float(u << 16);
  r.y = __uint_as_float(u & 0xffff0000u);
  return r;
}

// x[i,:] = memory_table[n_id[i],:]
__global__ void k_gather(const float* __restrict__ mem, const int* __restrict__ n_id,
                         float* __restrict__ x, int N) {
  int row = blockIdx.x * 4 + (threadIdx.x >> 6);
  if (row >= N) return;
  int lane = threadIdx.x & 63;
  const float2* s = (const float2*)(mem + (size_t)n_id[row] * D);
  float2* d = (float2*)(x + (size_t)row * D);
  d[lane] = s[lane];
}

// Convert weights to bf16, transposed [n][k]. Per layer: WqT,WkT,WvT,WsT (128x128)
// then WeT (128x96, k>=73 zero). Layer stride 77824 elems.
__global__ void k_prep_w(const float* Wq1, const float* Wk1, const float* Wv1,
                         const float* Ws1, const float* We1,
                         const float* Wq2, const float* Wk2, const float* Wv2,
                         const float* Ws2, const float* We2,
                         unsigned short* __restrict__ wt) {
  int i = blockIdx.x * 256 + threadIdx.x;
  if (i >= 2 * 77824) return;
  int l = i / 77824, j = i - l * 77824;
  const float* Wm[10] = {Wq1, Wk1, Wv1, Ws1, We1, Wq2, Wk2, Wv2, Ws2, We2};
  float val;
  if (j < 65536) {
    int m = j >> 14, idx = j & 16383, n = idx >> 7, k = idx & 127;
    val = Wm[l * 5 + m][k * 128 + n];
  } else {
    int jj = j - 65536, n = jj / 96, k = jj - (jj / 96) * 96;
    val = (k < 73) ? Wm[l * 5 + 4][k * 128 + n] : 0.f;
  }
  wt[i] = f2b(val);
}

// ---- CSR build ----
__global__ void k_hist(const int* __restrict__ dst, int* __restrict__ cnt, int E) {
  int t = blockIdx.x * 256 + threadIdx.x;
  if (t < E) atomicAdd(&cnt[dst[t]], 1);
}

#define SCAN_T 1024
__global__ __launch_bounds__(SCAN_T) void k_scan(const int* __restrict__ cnt,
                                                 int* __restrict__ rowptr,
                                                 int* __restrict__ cursor, int N) {
  __shared__ int part[SCAN_T];
  int tid = threadIdx.x;
  int chunk = (N + SCAN_T - 1) / SCAN_T;
  int b = tid * chunk, e = min(b + chunk, N);
  int s = 0;
  for (int i = b; i < e; i++) s += cnt[i];
  part[tid] = s;
  __syncthreads();
  for (int off = 1; off < SCAN_T; off <<= 1) {
    int v = (tid >= off) ? part[tid - off] : 0;
    __syncthreads();
    part[tid] += v;
    __syncthreads();
  }
  int base = (tid == 0) ? 0 : part[tid - 1];
  for (int i = b; i < e; i++) {
    rowptr[i] = base; cursor[i] = base;
    base += cnt[i];
  }
  if (tid == SCAN_T - 1) rowptr[N] = base;
}

__global__ void k_scatter(const int* __restrict__ dst, int* __restrict__ cursor,
                          int* __restrict__ perm, int E) {
  int t = blockIdx.x * 256 + threadIdx.x;
  if (t < E) {
    int pos = atomicAdd(&cursor[dst[t]], 1);
    perm[pos] = t;
  }
}

// q,k,v (bf16) and sk=x@Ws+bs (f32 skip) via MFMA. 64 rows/block.
__global__ __launch_bounds__(256) void k_lin4_mfma(
    const float* __restrict__ x, const unsigned short* __restrict__ wt,
    const float* __restrict__ bq, const float* __restrict__ bk,
    const float* __restrict__ bv, const float* __restrict__ bs,
    unsigned short* __restrict__ q, unsigned short* __restrict__ k,
    unsigned short* __restrict__ v, float* __restrict__ sk, int N) {
  __shared__ unsigned short xS[64 * 136];
  __shared__ unsigned short wS[128 * 136];
  int r0 = blockIdx.x * 64;
  int tid = threadIdx.x;
  for (int ch = tid; ch < 2048; ch += 256) {  // stage x fp32->bf16
    int r = ch >> 5, c4 = ch & 31;
    float4 xv = ((const float4*)(x + (size_t)(r0 + r) * D))[c4];
    unsigned short* dstp = &xS[r * 136 + c4 * 4];
    dstp[0] = f2b(xv.x); dstp[1] = f2b(xv.y); dstp[2] = f2b(xv.z); dstp[3] = f2b(xv.w);
  }
  int wave = tid >> 6, lane = tid & 63;
  int mrow = lane & 15, kgrp = lane >> 4;
  const float* bias[4] = {bq, bk, bv, bs};
  for (int mi = 0; mi < 4; mi++) {
    __syncthreads();
    const uint4* wg = (const uint4*)(wt + mi * 16384);
    for (int ch = tid; ch < 2048; ch += 256) {
      int n = ch >> 4, k8 = (ch & 15) << 3;
      *(uint4*)&wS[n * 136 + k8] = wg[ch];
    }
    __syncthreads();
    f32x4 acc[8];
#pragma unroll
    for (int nt = 0; nt < 8; nt++) {
      float b = bias[mi][mrow + 16 * nt];
      acc[nt] = (f32x4){b, b, b, b};
    }
#pragma unroll
    for (int kt = 0; kt < 4; kt++) {
      bf16x8 a = *(const bf16x8*)&xS[(wave * 16 + mrow) * 136 + kt * 32 + kgrp * 8];
#pragma unroll
      for (int nt = 0; nt < 8; nt++) {
        bf16x8 b = *(const bf16x8*)&wS[(mrow + 16 * nt) * 136 + kt * 32 + kgrp * 8];
        acc[nt] = __builtin_amdgcn_mfma_f32_16x16x32_bf16(a, b, acc[nt], 0, 0, 0);
      }
    }
    int row0 = r0 + wave * 16 + kgrp * 4;
    if (mi < 3) {
      unsigned short* o = (mi == 0) ? q : ((mi == 1) ? k : v);
#pragma unroll
      for (int nt = 0; nt < 8; nt++) {
        int col = mrow + 16 * nt;
#pragma unroll
        for (int r = 0; r < 4; r++)
          if (row0 + r < N) o[(size_t)(row0 + r) * D + col] = f2b(acc[nt][r]);
      }
    } else {
#pragma unroll
      for (int nt = 0; nt < 8; nt++) {
        int col = mrow + 16 * nt;
#pragma unroll
        for (int r = 0; r < 4; r++)
          if (row0 + r < N) sk[(size_t)(row0 + r) * D + col] = acc[nt][r];
      }
    }
  }
}

// e = pe @ We (bf16 out). pe built in LDS from ea + et_emb. 64 edges/block.
__global__ __launch_bounds__(256) void k_egemm_mfma(
    const float* __restrict__ ea, const float* __restrict__ et_emb,
    const unsigned short* __restrict__ weT, unsigned short* __restrict__ e, int E) {
  __shared__ unsigned short pS[64 * 104];
  __shared__ unsigned short wS[128 * 104];
  int e0 = blockIdx.x * 64;
  int tid = threadIdx.x;
  const uint4* wg = (const uint4*)weT;
  for (int ch = tid; ch < 1536; ch += 256) {
    int n = ch / 12, k8 = (ch % 12) << 3;
    *(uint4*)&wS[n * 104 + k8] = wg[ch];
  }
  for (int t = tid; t < 64 * 66; t += 256) {
    int r = t / 66, j = t - (t / 66) * 66;
    float val = ea[(size_t)(e0 + r) * 66 + j];
    if (j < 3) pS[r * 104 + j] = f2b(val);
    else if (j == 3) {
      int et = (int)val;
#pragma unroll
      for (int u = 0; u < 8; u++) pS[r * 104 + 65 + u] = f2b(et_emb[et * 8 + u]);
    } else pS[r * 104 + j - 1] = f2b(val);
  }
  for (int t = tid; t < 64 * 23; t += 256) {  // zero pad k=73..95
    int r = t / 23, j = 73 + t - (t / 23) * 23;
    pS[r * 104 + j] = 0;
  }
  __syncthreads();
  int wave = tid >> 6, lane = tid & 63;
  int mrow = lane & 15, kgrp = lane >> 4;
  f32x4 acc[8] = {};
#pragma unroll
  for (int kt = 0; kt < 3; kt++) {
    bf16x8 a = *(const bf16x8*)&pS[(wave * 16 + mrow) * 104 + kt * 32 + kgrp * 8];
#pragma unroll
    for (int nt = 0; nt < 8; nt++) {
      bf16x8 b = *(const bf16x8*)&wS[(mrow + 16 * nt) * 104 + kt * 32 + kgrp * 8];
      acc[nt] = __builtin_amdgcn_mfma_f32_16x16x32_bf16(a, b, acc[nt], 0, 0, 0);
    }
  }
  int row0 = e0 + wave * 16 + kgrp * 4;
#pragma unroll
  for (int nt = 0; nt < 8; nt++) {
    int col = mrow + 16 * nt;
#pragma unroll
    for (int r = 0; r < 4; r++)
      if (row0 + r < E) e[(size_t)(row0 + r) * D + col] = f2b(acc[nt][r]);
  }
}

// Fused attention per dst node: online softmax over CSR neighborhood, no atomics.
// out[d] = skip[d] + sum(alpha*(v[src]+e));  relu optionally fused.
__global__ void k_attn(const unsigned short* __restrict__ q,
                       const unsigned short* __restrict__ kmat,
                       const unsigned short* __restrict__ vmat,
                       const unsigned short* __restrict__ e,
                       const int* __restrict__ src, const int* __restrict__ perm,
                       const int* __restrict__ rowptr,
                       const float* __restrict__ skip, float* __restrict__ outp,
                       int N, int relu) {
  int d = blockIdx.x * 4 + (threadIdx.x >> 6);
  if (d >= N) return;
  int lane = threadIdx.x & 63;
  unsigned qv = ((const unsigned*)q)[(size_t)d * 64 + lane];
  float2 qf = b2f2(qv);
  float m = -3.4e38f, l = 0.f, o0 = 0.f, o1 = 0.f;
  int beg = rowptr[d], end = rowptr[d + 1];
  int edge = (beg < end) ? perm[beg] : 0;
  int s = (beg < end) ? src[edge] : 0;
  for (int j = beg; j < end; j++) {
    // prefetch next edge's indices to overlap the dependent-load chain
    int nedge = (j + 1 < end) ? perm[j + 1] : 0;
    unsigned kv = ((const unsigned*)kmat)[(size_t)s * 64 + lane];
    unsigned ev = ((const unsigned*)e)[(size_t)edge * 64 + lane];
    unsigned vv = ((const unsigned*)vmat)[(size_t)s * 64 + lane];
    int ns = (j + 1 < end) ? src[nedge] : 0;
    float2 kf = b2f2(kv), ef = b2f2(ev), vf = b2f2(vv);
    float p = qf.x * (kf.x + ef.x) + qf.y * (kf.y + ef.y);
    p += __shfl_xor(p, 8); p += __shfl_xor(p, 4);
    p += __shfl_xor(p, 2); p += __shfl_xor(p, 1);
    float sv = p * SCALE;  // uniform across the 16-lane head group
    float mn = fmaxf(m, sv);
    float scale = __expf(m - mn);   // first iter: exp(-inf) -> 0
    float ex = __expf(sv - mn);
    l = l * scale + ex;
    o0 = o0 * scale + ex * (vf.x + ef.x);
    o1 = o1 * scale + ex * (vf.y + ef.y);
    m = mn;
    edge = nedge; s = ns;
  }
  float inv = 1.f / (l + 1e-16f);
  float2 skv = ((const float2*)(skip + (size_t)d * D))[lane];
  float r0 = skv.x + o0 * inv;
  float r1 = skv.y + o1 * inv;
  if (relu) { r0 = fmaxf(r0, 0.f); r1 = fmaxf(r1, 0.f); }
  ((float2*)(outp + (size_t)d * D))[lane] = make_float2(r0, r1);
}

extern "C" void kernel_launch(void* const* d_in, const int* in_sizes, int n_in,
                              void* d_out, int out_size, void* d_ws, size_t ws_size,
                              hipStream_t stream) {
  const float* mem  = (const float*)d_in[0];
  const float* ea   = (const float*)d_in[1];
  const float* etem = (const float*)d_in[2];
  const float* W[18];
  for (int i = 0; i < 18; i++) W[i] = (const float*)d_in[3 + i];
  const int* n_id = (const int*)d_in[21];
  const int* eidx = (const int*)d_in[22];
  const int N = in_sizes[21];
  const int E = in_sizes[22] / 2;
  const int* srcp = eidx;
  const int* dstp = eidx + E;

  // workspace layout
  float* x0 = (float*)d_ws;                           // N*128 f32
  float* x1 = x0 + (size_t)N * D;                     // N*128 f32
  float* sk = x1 + (size_t)N * D;                     // N*128 f32 (skip)
  unsigned short* q = (unsigned short*)(sk + (size_t)N * D);  // N*128 bf16
  unsigned short* k = q + (size_t)N * D;
  unsigned short* v = k + (size_t)N * D;
  unsigned short* e = v + (size_t)N * D;              // E*128 bf16
  unsigned short* wt = e + (size_t)E * D;             // 2*77824 bf16
  int* cnt    = (int*)(wt + 2 * 77824);               // N
  int* rowptr = cnt + N;                              // N+1
  int* cursor = rowptr + N + 1;                       // N
  int* perm   = cursor + N;                           // E

  float* out = (float*)d_out;
  dim3 b256(256);

  // CSR build (dst identical for both layers)
  hipMemsetAsync(cnt, 0, (size_t)N * sizeof(int), stream);
  k_hist<<<dim3((E + 255) / 256), b256, 0, stream>>>(dstp, cnt, E);
  k_scan<<<dim3(1), dim3(SCAN_T), 0, stream>>>(cnt, rowptr, cursor, N);
  k_scatter<<<dim3((E + 255) / 256), b256, 0, stream>>>(dstp, cursor, perm, E);

  k_prep_w<<<dim3((2 * 77824 + 255) / 256), b256, 0, stream>>>(
      W[0], W[1], W[2], W[4], W[3], W[9], W[10], W[11], W[13], W[12], wt);
  k_gather<<<dim3((N + 3) / 4), b256, 0, stream>>>(mem, n_id, x0, N);

  for (int layer = 0; layer < 2; layer++) {
    const float* bq = W[layer * 9 + 5];
    const float* bk = W[layer * 9 + 6];
    const float* bv = W[layer * 9 + 7];
    const float* bs = W[layer * 9 + 8];
    const float* xc = (layer == 0) ? x0 : x1;
    float* outl = (layer == 0) ? x1 : out;
    const unsigned short* wtl = wt + (size_t)layer * 77824;

    k_lin4_mfma<<<dim3((N + 63) / 64), b256, 0, stream>>>(
        xc, wtl, bq, bk, bv, bs, q, k, v, sk, N);
    k_egemm_mfma<<<dim3((E + 63) / 64), b256, 0, stream>>>(
        ea, etem, wtl + 65536, e, E);
    k_attn<<<dim3((N + 3) / 4), b256, 0, stream>>>(
        q, k, v, e, srcp, perm, rowptr, sk, outl, N, layer == 0 ? 1 : 0);
  }
}